// Round 9
// baseline (145.925 us; speedup 1.0000x reference)
//
#include <hip/hip_runtime.h>

typedef short s8v __attribute__((ext_vector_type(8)));
typedef float f4v __attribute__((ext_vector_type(4)));

#define NB 4
#define LQ 2048
#define LKK 2048
#define XS 1024
#define PDD 128

#define PST 68    // P LDS stride (floats): 272B = 16*17 -> 2-way banks (free)
#define AST 132   // acc-partial LDS stride (floats)

__device__ __forceinline__ ushort f2bf(float x) {
  union { float f; uint u; } v; v.f = x;
  uint r = (v.u + 0x7fffu + ((v.u >> 16) & 1u)) >> 16;
  return (ushort)r;
}

// Fragment-contiguous layouts:
//   qb2/kb2: elem(b,row,d) -> ((((b*128 + row>>4)*4 + d>>5)*4 + (d>>3)&3)*16 + row&15)*8 + d&7
//   vb2:     elem(b,key,d) -> ((((b*64 + key>>5)*8 + d>>4)*4 + (key>>3)&3)*16 + d&15)*8 + key&7
//   Wt2:     elem(p,col,k) -> p*131072 + ((col>>4)*32 + k>>5)*512 + ((k>>3)&3)*128 + (col&15)*8 + k&7
// Every MFMA fragment load is lane*8 contiguous -> one dense 1KB wave transaction.

// ---------------- W transpose + bf16 cast into Wt2 fragment layout ----------------
__global__ __launch_bounds__(256) void k_wtrans(const float* __restrict__ Wq,
                                                const float* __restrict__ Wk,
                                                const float* __restrict__ Wv,
                                                ushort* __restrict__ Wt) {
  int p = blockIdx.y;
  const float* W = (p == 0) ? Wq : (p == 1) ? Wk : Wv;
  ushort* out = Wt + (size_t)p * (PDD * XS);
  int t = threadIdx.x;
  int n = t >> 1;            // output col 0..127
  int kk0 = (t & 1) * 16;    // k sub-offset within 32-chunk
  int k0 = blockIdx.x * 32;  // k chunk base
  ushort tmp[16];
#pragma unroll
  for (int i = 0; i < 16; ++i) tmp[i] = f2bf(W[(size_t)(k0 + kk0 + i) * PDD + n]);
  uint4 u0, u1;
  u0.x = tmp[0] | ((uint)tmp[1] << 16);  u0.y = tmp[2] | ((uint)tmp[3] << 16);
  u0.z = tmp[4] | ((uint)tmp[5] << 16);  u0.w = tmp[6] | ((uint)tmp[7] << 16);
  u1.x = tmp[8] | ((uint)tmp[9] << 16);  u1.y = tmp[10] | ((uint)tmp[11] << 16);
  u1.z = tmp[12] | ((uint)tmp[13] << 16); u1.w = tmp[14] | ((uint)tmp[15] << 16);
  // Wt2: ct=n>>4, lc=n&15, kq=k0>>5, quad = (kk0>>3) then +1 for the next 8 k's
  int ct = n >> 4, lc = n & 15, kq = k0 >> 5;
  ushort* base = out + ((size_t)(ct * 32 + kq)) * 512 + (kk0 >> 3) * 128 + lc * 8;
  *(uint4*)base = u0;            // k = k0+kk0 .. +7   (quad kk0>>3)
  *(uint4*)(base + 128) = u1;    // k = k0+kk0+8 .. +15 (quad kk0>>3 + 1)
}

// ---------------- projections: kind 0: q=(x@Wq+bq)*scale ; kind 1: k AND v --------
// Single-barrier structure (the k_attn levers applied to k_proj):
//  - stage the FULL 32x1024 A-tile fp32->bf16 into LDS once (66KB, stride 1032
//    bf16 -> balanced banks), ONE __syncthreads, then a barrier-free compute
//    loop over 32 K-chunks (was: 16 steps x 2 barriers with vmcnt(0) drains).
//  - B fragments read per-lane DENSE from L2-resident Wt2 (no B staging/LDS).
//  - k+v FUSED in one block: y-tile staged once feeds both Wk and Wv (halves
//    y HBM reads and staging work).
// Grid 512 = 2 blocks/CU; XCD-pinned (batch b -> XCD pair {2b,2b+1}) so k/v
// writes land in the L2s k_attn reads; q/kv interleaved per XCD for balance.
__global__ __launch_bounds__(256, 2) void k_proj(const float* __restrict__ x,
                                                 const float* __restrict__ y,
                                                 const ushort* __restrict__ Wt,
                                                 const float* __restrict__ bq,
                                                 const float* __restrict__ bk,
                                                 const float* __restrict__ bv,
                                                 ushort* __restrict__ qo,
                                                 ushort* __restrict__ ko,
                                                 ushort* __restrict__ vt) {
  __shared__ ushort As[32 * 1032];  // 32 rows x 1024 bf16, stride 1032
  int bx = blockIdx.x;              // [0,512)
  int xcd = bx & 7;                 // assumes linear-id % 8 XCD round-robin
  int b = xcd >> 1;                 // batch -> XCD pair
  int half = xcd & 1;
  int idx = bx >> 3;                // [0,64) per XCD
  int kind = idx & 1;               // 0: q from x ; 1: k+v from y
  int rt = (idx >> 1) + half * 32;  // row-tile [0,64) within batch
  int row0 = b * 2048 + rt * 32;
  const float* in = kind ? y : x;
  int t = threadIdx.x, wave = t >> 6, lane = t & 63, quad = lane >> 4, lc = lane & 15;

  {  // stage A: thread t -> row t>>3, 128 consecutive cols (t&7)*128
    int r = t >> 3, c0 = (t & 7) * 128;
    const float* src = in + (size_t)(row0 + r) * XS + c0;
    ushort* dst = &As[r * 1032 + c0];
#pragma unroll
    for (int s = 0; s < 8; ++s) {
      float4 f0 = *(const float4*)(src + s * 16);
      float4 f1 = *(const float4*)(src + s * 16 + 4);
      float4 f2 = *(const float4*)(src + s * 16 + 8);
      float4 f3 = *(const float4*)(src + s * 16 + 12);
      uint4 p0, p1;
      p0.x = f2bf(f0.x) | ((uint)f2bf(f0.y) << 16);
      p0.y = f2bf(f0.z) | ((uint)f2bf(f0.w) << 16);
      p0.z = f2bf(f1.x) | ((uint)f2bf(f1.y) << 16);
      p0.w = f2bf(f1.z) | ((uint)f2bf(f1.w) << 16);
      p1.x = f2bf(f2.x) | ((uint)f2bf(f2.y) << 16);
      p1.y = f2bf(f2.z) | ((uint)f2bf(f2.w) << 16);
      p1.z = f2bf(f3.x) | ((uint)f2bf(f3.y) << 16);
      p1.w = f2bf(f3.z) | ((uint)f2bf(f3.w) << 16);
      *(uint4*)(dst + s * 16) = p0;
      *(uint4*)(dst + s * 16 + 8) = p1;
    }
  }
  __syncthreads();  // the ONLY barrier

  const f4v z4 = {0.f, 0.f, 0.f, 0.f};
  f4v acc0[2][2], acc1[2][2];
#pragma unroll
  for (int m = 0; m < 2; ++m)
#pragma unroll
    for (int n = 0; n < 2; ++n) { acc0[m][n] = z4; acc1[m][n] = z4; }

  // weight panels (Wt2): kind 0 -> Wq ; kind 1 -> Wk (acc0) + Wv (acc1)
  const ushort* w0 = Wt + (size_t)(kind ? 1 : 0) * (PDD * XS) + lane * 8;
  const ushort* w1 = Wt + (size_t)2 * (PDD * XS) + lane * 8;
  int ct0 = wave * 2;

#pragma unroll 4
  for (int kq = 0; kq < 32; ++kq) {
    s8v a0 = *(const s8v*)&As[lc * 1032 + kq * 32 + quad * 8];
    s8v a1 = *(const s8v*)&As[(16 + lc) * 1032 + kq * 32 + quad * 8];
    s8v b00 = *(const s8v*)(w0 + ((size_t)(ct0 * 32 + kq)) * 512);
    s8v b01 = *(const s8v*)(w0 + ((size_t)((ct0 + 1) * 32 + kq)) * 512);
    acc0[0][0] = __builtin_amdgcn_mfma_f32_16x16x32_bf16(a0, b00, acc0[0][0], 0, 0, 0);
    acc0[0][1] = __builtin_amdgcn_mfma_f32_16x16x32_bf16(a0, b01, acc0[0][1], 0, 0, 0);
    acc0[1][0] = __builtin_amdgcn_mfma_f32_16x16x32_bf16(a1, b00, acc0[1][0], 0, 0, 0);
    acc0[1][1] = __builtin_amdgcn_mfma_f32_16x16x32_bf16(a1, b01, acc0[1][1], 0, 0, 0);
    if (kind) {
      s8v b10 = *(const s8v*)(w1 + ((size_t)(ct0 * 32 + kq)) * 512);
      s8v b11 = *(const s8v*)(w1 + ((size_t)((ct0 + 1) * 32 + kq)) * 512);
      acc1[0][0] = __builtin_amdgcn_mfma_f32_16x16x32_bf16(a0, b10, acc1[0][0], 0, 0, 0);
      acc1[0][1] = __builtin_amdgcn_mfma_f32_16x16x32_bf16(a0, b11, acc1[0][1], 0, 0, 0);
      acc1[1][0] = __builtin_amdgcn_mfma_f32_16x16x32_bf16(a1, b10, acc1[1][0], 0, 0, 0);
      acc1[1][1] = __builtin_amdgcn_mfma_f32_16x16x32_bf16(a1, b11, acc1[1][1], 0, 0, 0);
    }
  }

  const float qscale = 0.08838834764831845f;  // 1/sqrt(128) folded into q
  int rloc = rt * 32;
  if (kind == 0) {
    // q -> qb2 (scaled)
#pragma unroll
    for (int m = 0; m < 2; ++m) {
      int qt = (rloc >> 4) + m;
#pragma unroll
      for (int n = 0; n < 2; ++n) {
        int col = wave * 32 + n * 16 + lc;
        float bb = bq[col];
        size_t base = ((((size_t)(b * 128 + qt) * 4 + wave) * 4 + (n * 2 + (lc >> 3))) * 16 +
                       quad * 4) * 8 + (lc & 7);
#pragma unroll
        for (int g = 0; g < 4; ++g)
          qo[base + (size_t)g * 8] = f2bf((acc0[m][n][g] + bb) * qscale);
      }
    }
  } else {
    // k -> kb2
#pragma unroll
    for (int m = 0; m < 2; ++m) {
      int qt = (rloc >> 4) + m;
#pragma unroll
      for (int n = 0; n < 2; ++n) {
        int col = wave * 32 + n * 16 + lc;
        float bb = bk[col];
        size_t base = ((((size_t)(b * 128 + qt) * 4 + wave) * 4 + (n * 2 + (lc >> 3))) * 16 +
                       quad * 4) * 8 + (lc & 7);
#pragma unroll
        for (int g = 0; g < 4; ++g)
          ko[base + (size_t)g * 8] = f2bf(acc0[m][n][g] + bb);
      }
    }
    // v -> vb2 (4 consecutive keys per lane -> 8B store)
#pragma unroll
    for (int m = 0; m < 2; ++m) {
      int rr = rloc + m * 16 + quad * 4;
      int kchunk = rr >> 5, qv = (rr >> 3) & 3, jj0 = rr & 7;
#pragma unroll
      for (int n = 0; n < 2; ++n) {
        int col = wave * 32 + n * 16 + lc;
        int dt = wave * 2 + n;
        float bb = bv[col];
        ushort4 pk;
        pk.x = f2bf(acc1[m][n][0] + bb);
        pk.y = f2bf(acc1[m][n][1] + bb);
        pk.z = f2bf(acc1[m][n][2] + bb);
        pk.w = f2bf(acc1[m][n][3] + bb);
        size_t off = ((((size_t)(b * 64 + kchunk) * 8 + dt) * 4 + qv) * 16 + lc) * 8 + jj0;
        *(ushort4*)&vt[off] = pk;
      }
    }
  }
}

// ------- fused attention: 32 q-rows/block (2 M-tiles/wave), KV-split-8 ----------
// (round-8, unchanged) 256 blocks x 512 thr, launch_bounds(512,2), kf[16]/vf[16]
// dense fragment-contiguous batching, fixed-ref softmax, XCD pinning.
__global__ __launch_bounds__(512, 2) void k_attn(const ushort* __restrict__ qg,
                                                 const ushort* __restrict__ kg,
                                                 const ushort* __restrict__ vtg,
                                                 const int* __restrict__ maskp,
                                                 float* __restrict__ out) {
  __shared__ float smem[8 * 32 * PST];  // loop: Ps[8][32*PST]; epilogue: accS[8][16*AST]
  __shared__ float lS[8][2][16];
  int bx = blockIdx.x;
  int xcd = bx & 7;                       // assumes linear-id % 8 XCD round-robin
  int b = xcd >> 1;                       // batch -> XCD pair
  int q0 = ((bx >> 3) * 2 + (xcd & 1)) * 32;
  int t = threadIdx.x;
  int wave = t >> 6, lane = t & 63, quad = lane >> 4, lc = lane & 15;
  int domask = *maskp;
  float* Psw = smem + wave * (32 * PST);  // per-wave P buffer, 32 rows (loop only)

  // Q A-frags: dense fragment loads (lane*8 contiguous)
  const ushort* qB = qg + ((size_t)(b * 128 + (q0 >> 4))) * 2048 + lane * 8;
  s8v aq[2][4];
#pragma unroll
  for (int m = 0; m < 2; ++m)
#pragma unroll
    for (int kc = 0; kc < 4; ++kc)
      aq[m][kc] = *(const s8v*)(qB + m * 2048 + kc * 512);

  const f4v z4 = {0.f, 0.f, 0.f, 0.f};
  f4v acc[2][8];
#pragma unroll
  for (int m = 0; m < 2; ++m)
#pragma unroll
    for (int i = 0; i < 8; ++i) acc[m][i] = z4;
  float rs[2][4] = {{0.f, 0.f, 0.f, 0.f}, {0.f, 0.f, 0.f, 0.f}};

#pragma unroll 1
  for (int i = 0; i < 4; ++i) {
    int kt = wave + i * 8;

    // batch-issue ALL 16 K-fragment loads — 16KB CONTIGUOUS per wave
    const ushort* kB = kg + ((size_t)(b * 128 + i * 32 + wave * 4)) * 2048 + lane * 8;
    s8v kf[16];
#pragma unroll
    for (int f = 0; f < 16; ++f) kf[f] = *(const s8v*)(kB + f * 512);

    // S = Q K^T for both M-tiles; each K fragment used twice
    f4v sf[2][4];
#pragma unroll
    for (int nt = 0; nt < 4; ++nt) {
      f4v s0 = z4, s1 = z4;
#pragma unroll
      for (int kc = 0; kc < 4; ++kc) {
        s0 = __builtin_amdgcn_mfma_f32_16x16x32_bf16(aq[0][kc], kf[nt * 4 + kc], s0, 0, 0, 0);
        s1 = __builtin_amdgcn_mfma_f32_16x16x32_bf16(aq[1][kc], kf[nt * 4 + kc], s1, 0, 0, 0);
      }
      sf[0][nt] = s0;
      sf[1][nt] = s1;
    }

    // batch-issue ALL 16 V-fragment loads (dense 16KB contiguous); kf dead now.
    // sched_barrier(0) pins issues ABOVE the softmax so latency hides under it.
    const ushort* vB = vtg + ((size_t)(b * 64 + i * 16 + wave * 2)) * 4096 + lane * 8;
    s8v vf[16];
#pragma unroll
    for (int f = 0; f < 16; ++f) vf[f] = *(const s8v*)(vB + f * 512);
    __builtin_amdgcn_sched_barrier(0);

    // P = exp(S) (fixed reference 0), accumulate per-lane row sums, store P
#pragma unroll
    for (int m = 0; m < 2; ++m)
#pragma unroll
      for (int g = 0; g < 4; ++g) {
        int rg = q0 + m * 16 + quad * 4 + g;
#pragma unroll
        for (int nt = 0; nt < 4; ++nt) {
          float pv = __expf(sf[m][nt][g]);
          rs[m][g] += pv;  // l over ALL keys (mask is post-softmax, no renorm)
          int jg = kt * 64 + nt * 16 + lc;
          if (domask && (jg <= rg)) pv = 0.f;
          Psw[(m * 16 + quad * 4 + g) * PST + nt * 16 + lc] = pv;
        }
      }

    // P x V: each V fragment feeds both M-tiles' MFMAs
#pragma unroll
    for (int jc = 0; jc < 2; ++jc)
#pragma unroll
      for (int m = 0; m < 2; ++m) {
        const float* pp = &Psw[(m * 16 + lc) * PST + jc * 32 + quad * 8];
        float4 p0 = *(const float4*)pp;
        float4 p1 = *(const float4*)(pp + 4);
        s8v ap;
        ap[0] = (short)f2bf(p0.x); ap[1] = (short)f2bf(p0.y);
        ap[2] = (short)f2bf(p0.z); ap[3] = (short)f2bf(p0.w);
        ap[4] = (short)f2bf(p1.x); ap[5] = (short)f2bf(p1.y);
        ap[6] = (short)f2bf(p1.z); ap[7] = (short)f2bf(p1.w);
#pragma unroll
        for (int dt = 0; dt < 8; ++dt) {
          acc[m][dt] = __builtin_amdgcn_mfma_f32_16x16x32_bf16(ap, vf[jc * 8 + dt], acc[m][dt], 0, 0, 0);
        }
      }
  }

  // reduce per-lane row sums across the 16 lc lanes (once, after the loop)
#pragma unroll
  for (int off = 8; off >= 1; off >>= 1)
#pragma unroll
    for (int m = 0; m < 2; ++m)
#pragma unroll
      for (int g = 0; g < 4; ++g) rs[m][g] += __shfl_xor(rs[m][g], off, 64);

  // all waves done with Ps before the region is reused as accS
  __syncthreads();
  if (lc == 0) {
#pragma unroll
    for (int m = 0; m < 2; ++m)
#pragma unroll
      for (int g = 0; g < 4; ++g) lS[wave][m][quad * 4 + g] = rs[m][g];
  }

  // merge the 8 per-wave partials (plain sums — same softmax reference for all),
  // one 16-row M-tile at a time; FULLY unrolled so acc[] indices stay static.
#pragma unroll
  for (int m = 0; m < 2; ++m) {
#pragma unroll
    for (int dt = 0; dt < 8; ++dt)
#pragma unroll
      for (int g = 0; g < 4; ++g)
        smem[wave * (16 * AST) + (quad * 4 + g) * AST + dt * 16 + lc] = acc[m][dt][g];
    __syncthreads();
    {
      int row = t >> 5, c0 = (t & 31) * 4;
      float L = 0.f;
      float ox = 0.f, oy = 0.f, oz = 0.f, ow = 0.f;
#pragma unroll
      for (int p = 0; p < 8; ++p) {
        L += lS[p][m][row];
        const float* a = &smem[p * (16 * AST) + row * AST + c0];
        float4 xv = *(const float4*)a;
        ox += xv.x; oy += xv.y; oz += xv.z; ow += xv.w;
      }
      float inv = 1.0f / L;
      float4 o;
      o.x = ox * inv; o.y = oy * inv; o.z = oz * inv; o.w = ow * inv;
      float* op = out + ((size_t)(b * LQ + q0 + m * 16 + row)) * PDD + c0;
      *(float4*)op = o;
    }
    __syncthreads();  // merge reads done before next phase overwrites accS
  }
}

extern "C" void kernel_launch(void* const* d_in, const int* in_sizes, int n_in,
                              void* d_out, int out_size, void* d_ws, size_t ws_size,
                              hipStream_t stream) {
  const float* x  = (const float*)d_in[0];
  const float* y  = (const float*)d_in[1];
  const float* Wq = (const float*)d_in[2];
  const float* bq = (const float*)d_in[3];
  const float* Wk = (const float*)d_in[4];
  const float* bk = (const float*)d_in[5];
  const float* Wv = (const float*)d_in[6];
  const float* bv = (const float*)d_in[7];
  const int* mask = (const int*)d_in[8];
  char* ws = (char*)d_ws;
  ushort* qb = (ushort*)(ws);                     // qb2: [B][128][4][4][16][8] bf16
  ushort* kb = (ushort*)(ws + (size_t)(1 << 21)); // kb2: [B][128][4][4][16][8] bf16
  ushort* vt = (ushort*)(ws + (size_t)(2 << 21)); // vb2: [B][64][8][4][16][8] bf16
  ushort* Wt = (ushort*)(ws + (size_t)(3 << 21)); // Wt2: fragment-contiguous [3][...]
  float* out = (float*)d_out;

  hipLaunchKernelGGL(k_wtrans, dim3(32, 3), dim3(256), 0, stream, Wq, Wk, Wv, Wt);
  hipLaunchKernelGGL(k_proj, dim3(512), dim3(256), 0, stream, x, y, Wt, bq, bk, bv, qb, kb, vt);
  hipLaunchKernelGGL(k_attn, dim3(256), dim3(512), 0, stream, qb, kb, vt, mask, out);
}

// Round 10
// 142.559 us; speedup vs baseline: 1.0236x; 1.0236x over previous
//
#include <hip/hip_runtime.h>

typedef short s8v __attribute__((ext_vector_type(8)));
typedef float f4v __attribute__((ext_vector_type(4)));

#define NB 4
#define LQ 2048
#define LKK 2048
#define XS 1024
#define PDD 128

#define PST 68    // P LDS stride (floats): 272B = 16*17 -> 2-way banks (free)
#define AST 132   // acc-partial LDS stride (floats)

__device__ __forceinline__ ushort f2bf(float x) {
  union { float f; uint u; } v; v.f = x;
  uint r = (v.u + 0x7fffu + ((v.u >> 16) & 1u)) >> 16;
  return (ushort)r;
}

// Fragment-contiguous layouts:
//   qb2/kb2: elem(b,row,d) -> ((((b*128 + row>>4)*4 + d>>5)*4 + (d>>3)&3)*16 + row&15)*8 + d&7
//   vb2:     elem(b,key,d) -> ((((b*64 + key>>5)*8 + d>>4)*4 + (key>>3)&3)*16 + d&15)*8 + key&7
//   Wt2:     elem(p,col,k) -> p*131072 + ((col>>4)*32 + k>>5)*512 + ((k>>3)&3)*128 + (col&15)*8 + k&7
// Every MFMA fragment load is lane*8 contiguous -> one dense 1KB wave transaction.

// ---------------- W transpose + bf16 cast into Wt2 fragment layout ----------------
__global__ __launch_bounds__(256) void k_wtrans(const float* __restrict__ Wq,
                                                const float* __restrict__ Wk,
                                                const float* __restrict__ Wv,
                                                ushort* __restrict__ Wt) {
  int p = blockIdx.y;
  const float* W = (p == 0) ? Wq : (p == 1) ? Wk : Wv;
  ushort* out = Wt + (size_t)p * (PDD * XS);
  int t = threadIdx.x;
  int n = t >> 1;            // output col 0..127
  int kk0 = (t & 1) * 16;    // k sub-offset within 32-chunk
  int k0 = blockIdx.x * 32;  // k chunk base
  ushort tmp[16];
#pragma unroll
  for (int i = 0; i < 16; ++i) tmp[i] = f2bf(W[(size_t)(k0 + kk0 + i) * PDD + n]);
  uint4 u0, u1;
  u0.x = tmp[0] | ((uint)tmp[1] << 16);  u0.y = tmp[2] | ((uint)tmp[3] << 16);
  u0.z = tmp[4] | ((uint)tmp[5] << 16);  u0.w = tmp[6] | ((uint)tmp[7] << 16);
  u1.x = tmp[8] | ((uint)tmp[9] << 16);  u1.y = tmp[10] | ((uint)tmp[11] << 16);
  u1.z = tmp[12] | ((uint)tmp[13] << 16); u1.w = tmp[14] | ((uint)tmp[15] << 16);
  // Wt2: ct=n>>4, lc=n&15, kq=k0>>5, quad = (kk0>>3) then +1 for the next 8 k's
  int ct = n >> 4, lc = n & 15, kq = k0 >> 5;
  ushort* base = out + ((size_t)(ct * 32 + kq)) * 512 + (kk0 >> 3) * 128 + lc * 8;
  *(uint4*)base = u0;            // k = k0+kk0 .. +7   (quad kk0>>3)
  *(uint4*)(base + 128) = u1;    // k = k0+kk0+8 .. +15 (quad kk0>>3 + 1)
}

// ---------------- projections: kind 0: q=(x@Wq+bq)*scale ; kind 1: k AND v --------
// Round-9 structure (single barrier, dense Wt2 B reads, fused k+v) with ONE
// change: COALESCED A-staging. Round-9 staged 128-consecutive-floats per
// thread, so each load instruction had lanes 512B apart = 64 line-requests
// per instr through the TA (the exact pattern whose fix bought k_attn -17us
// in round 8). Now lane t covers column-slice t*4 of each row: every wave
// load is 1KB contiguous (8 lines/instr), 8 rows batched in v[8] registers
// (static indexing) for 8-deep MLP, ds_write_b64 per lane (bandwidth-floor).
__global__ __launch_bounds__(256, 2) void k_proj(const float* __restrict__ x,
                                                 const float* __restrict__ y,
                                                 const ushort* __restrict__ Wt,
                                                 const float* __restrict__ bq,
                                                 const float* __restrict__ bk,
                                                 const float* __restrict__ bv,
                                                 ushort* __restrict__ qo,
                                                 ushort* __restrict__ ko,
                                                 ushort* __restrict__ vt) {
  __shared__ ushort As[32 * 1032];  // 32 rows x 1024 bf16, stride 1032
  int bx = blockIdx.x;              // [0,512)
  int xcd = bx & 7;                 // assumes linear-id % 8 XCD round-robin
  int b = xcd >> 1;                 // batch -> XCD pair
  int half = xcd & 1;
  int idx = bx >> 3;                // [0,64) per XCD
  int kind = idx & 1;               // 0: q from x ; 1: k+v from y
  int rt = (idx >> 1) + half * 32;  // row-tile [0,64) within batch
  int row0 = b * 2048 + rt * 32;
  const float* in = kind ? y : x;
  int t = threadIdx.x, wave = t >> 6, lane = t & 63, quad = lane >> 4, lc = lane & 15;

  {  // stage A coalesced: lane t covers float cols [t*4, t*4+4) of every row
    int c0 = t * 4;
    const float* src = in + (size_t)row0 * XS + c0;
#pragma unroll
    for (int rb = 0; rb < 4; ++rb) {
      float4 v0 = *(const float4*)(src + (size_t)(rb * 8 + 0) * XS);
      float4 v1 = *(const float4*)(src + (size_t)(rb * 8 + 1) * XS);
      float4 v2 = *(const float4*)(src + (size_t)(rb * 8 + 2) * XS);
      float4 v3 = *(const float4*)(src + (size_t)(rb * 8 + 3) * XS);
      float4 v4 = *(const float4*)(src + (size_t)(rb * 8 + 4) * XS);
      float4 v5 = *(const float4*)(src + (size_t)(rb * 8 + 5) * XS);
      float4 v6 = *(const float4*)(src + (size_t)(rb * 8 + 6) * XS);
      float4 v7 = *(const float4*)(src + (size_t)(rb * 8 + 7) * XS);
      uint2 pk;
#define STW(rr, vv)                                                        \
      pk.x = f2bf(vv.x) | ((uint)f2bf(vv.y) << 16);                        \
      pk.y = f2bf(vv.z) | ((uint)f2bf(vv.w) << 16);                        \
      *(uint2*)&As[(rb * 8 + rr) * 1032 + c0] = pk;
      STW(0, v0) STW(1, v1) STW(2, v2) STW(3, v3)
      STW(4, v4) STW(5, v5) STW(6, v6) STW(7, v7)
#undef STW
    }
  }
  __syncthreads();  // the ONLY barrier

  const f4v z4 = {0.f, 0.f, 0.f, 0.f};
  f4v acc0[2][2], acc1[2][2];
#pragma unroll
  for (int m = 0; m < 2; ++m)
#pragma unroll
    for (int n = 0; n < 2; ++n) { acc0[m][n] = z4; acc1[m][n] = z4; }

  // weight panels (Wt2): kind 0 -> Wq ; kind 1 -> Wk (acc0) + Wv (acc1)
  const ushort* w0 = Wt + (size_t)(kind ? 1 : 0) * (PDD * XS) + lane * 8;
  const ushort* w1 = Wt + (size_t)2 * (PDD * XS) + lane * 8;
  int ct0 = wave * 2;

#pragma unroll 4
  for (int kq = 0; kq < 32; ++kq) {
    s8v a0 = *(const s8v*)&As[lc * 1032 + kq * 32 + quad * 8];
    s8v a1 = *(const s8v*)&As[(16 + lc) * 1032 + kq * 32 + quad * 8];
    s8v b00 = *(const s8v*)(w0 + ((size_t)(ct0 * 32 + kq)) * 512);
    s8v b01 = *(const s8v*)(w0 + ((size_t)((ct0 + 1) * 32 + kq)) * 512);
    acc0[0][0] = __builtin_amdgcn_mfma_f32_16x16x32_bf16(a0, b00, acc0[0][0], 0, 0, 0);
    acc0[0][1] = __builtin_amdgcn_mfma_f32_16x16x32_bf16(a0, b01, acc0[0][1], 0, 0, 0);
    acc0[1][0] = __builtin_amdgcn_mfma_f32_16x16x32_bf16(a1, b00, acc0[1][0], 0, 0, 0);
    acc0[1][1] = __builtin_amdgcn_mfma_f32_16x16x32_bf16(a1, b01, acc0[1][1], 0, 0, 0);
    if (kind) {
      s8v b10 = *(const s8v*)(w1 + ((size_t)(ct0 * 32 + kq)) * 512);
      s8v b11 = *(const s8v*)(w1 + ((size_t)((ct0 + 1) * 32 + kq)) * 512);
      acc1[0][0] = __builtin_amdgcn_mfma_f32_16x16x32_bf16(a0, b10, acc1[0][0], 0, 0, 0);
      acc1[0][1] = __builtin_amdgcn_mfma_f32_16x16x32_bf16(a0, b11, acc1[0][1], 0, 0, 0);
      acc1[1][0] = __builtin_amdgcn_mfma_f32_16x16x32_bf16(a1, b10, acc1[1][0], 0, 0, 0);
      acc1[1][1] = __builtin_amdgcn_mfma_f32_16x16x32_bf16(a1, b11, acc1[1][1], 0, 0, 0);
    }
  }

  const float qscale = 0.08838834764831845f;  // 1/sqrt(128) folded into q
  int rloc = rt * 32;
  if (kind == 0) {
    // q -> qb2 (scaled)
#pragma unroll
    for (int m = 0; m < 2; ++m) {
      int qt = (rloc >> 4) + m;
#pragma unroll
      for (int n = 0; n < 2; ++n) {
        int col = wave * 32 + n * 16 + lc;
        float bb = bq[col];
        size_t base = ((((size_t)(b * 128 + qt) * 4 + wave) * 4 + (n * 2 + (lc >> 3))) * 16 +
                       quad * 4) * 8 + (lc & 7);
#pragma unroll
        for (int g = 0; g < 4; ++g)
          qo[base + (size_t)g * 8] = f2bf((acc0[m][n][g] + bb) * qscale);
      }
    }
  } else {
    // k -> kb2
#pragma unroll
    for (int m = 0; m < 2; ++m) {
      int qt = (rloc >> 4) + m;
#pragma unroll
      for (int n = 0; n < 2; ++n) {
        int col = wave * 32 + n * 16 + lc;
        float bb = bk[col];
        size_t base = ((((size_t)(b * 128 + qt) * 4 + wave) * 4 + (n * 2 + (lc >> 3))) * 16 +
                       quad * 4) * 8 + (lc & 7);
#pragma unroll
        for (int g = 0; g < 4; ++g)
          ko[base + (size_t)g * 8] = f2bf(acc0[m][n][g] + bb);
      }
    }
    // v -> vb2 (4 consecutive keys per lane -> 8B store)
#pragma unroll
    for (int m = 0; m < 2; ++m) {
      int rr = rloc + m * 16 + quad * 4;
      int kchunk = rr >> 5, qv = (rr >> 3) & 3, jj0 = rr & 7;
#pragma unroll
      for (int n = 0; n < 2; ++n) {
        int col = wave * 32 + n * 16 + lc;
        int dt = wave * 2 + n;
        float bb = bv[col];
        ushort4 pk;
        pk.x = f2bf(acc1[m][n][0] + bb);
        pk.y = f2bf(acc1[m][n][1] + bb);
        pk.z = f2bf(acc1[m][n][2] + bb);
        pk.w = f2bf(acc1[m][n][3] + bb);
        size_t off = ((((size_t)(b * 64 + kchunk) * 8 + dt) * 4 + qv) * 16 + lc) * 8 + jj0;
        *(ushort4*)&vt[off] = pk;
      }
    }
  }
}

// ------- fused attention: 32 q-rows/block (2 M-tiles/wave), KV-split-8 ----------
// (round-8, unchanged) 256 blocks x 512 thr, launch_bounds(512,2), kf[16]/vf[16]
// dense fragment-contiguous batching, fixed-ref softmax, XCD pinning.
__global__ __launch_bounds__(512, 2) void k_attn(const ushort* __restrict__ qg,
                                                 const ushort* __restrict__ kg,
                                                 const ushort* __restrict__ vtg,
                                                 const int* __restrict__ maskp,
                                                 float* __restrict__ out) {
  __shared__ float smem[8 * 32 * PST];  // loop: Ps[8][32*PST]; epilogue: accS[8][16*AST]
  __shared__ float lS[8][2][16];
  int bx = blockIdx.x;
  int xcd = bx & 7;                       // assumes linear-id % 8 XCD round-robin
  int b = xcd >> 1;                       // batch -> XCD pair
  int q0 = ((bx >> 3) * 2 + (xcd & 1)) * 32;
  int t = threadIdx.x;
  int wave = t >> 6, lane = t & 63, quad = lane >> 4, lc = lane & 15;
  int domask = *maskp;
  float* Psw = smem + wave * (32 * PST);  // per-wave P buffer, 32 rows (loop only)

  // Q A-frags: dense fragment loads (lane*8 contiguous)
  const ushort* qB = qg + ((size_t)(b * 128 + (q0 >> 4))) * 2048 + lane * 8;
  s8v aq[2][4];
#pragma unroll
  for (int m = 0; m < 2; ++m)
#pragma unroll
    for (int kc = 0; kc < 4; ++kc)
      aq[m][kc] = *(const s8v*)(qB + m * 2048 + kc * 512);

  const f4v z4 = {0.f, 0.f, 0.f, 0.f};
  f4v acc[2][8];
#pragma unroll
  for (int m = 0; m < 2; ++m)
#pragma unroll
    for (int i = 0; i < 8; ++i) acc[m][i] = z4;
  float rs[2][4] = {{0.f, 0.f, 0.f, 0.f}, {0.f, 0.f, 0.f, 0.f}};

#pragma unroll 1
  for (int i = 0; i < 4; ++i) {
    int kt = wave + i * 8;

    // batch-issue ALL 16 K-fragment loads — 16KB CONTIGUOUS per wave
    const ushort* kB = kg + ((size_t)(b * 128 + i * 32 + wave * 4)) * 2048 + lane * 8;
    s8v kf[16];
#pragma unroll
    for (int f = 0; f < 16; ++f) kf[f] = *(const s8v*)(kB + f * 512);

    // S = Q K^T for both M-tiles; each K fragment used twice
    f4v sf[2][4];
#pragma unroll
    for (int nt = 0; nt < 4; ++nt) {
      f4v s0 = z4, s1 = z4;
#pragma unroll
      for (int kc = 0; kc < 4; ++kc) {
        s0 = __builtin_amdgcn_mfma_f32_16x16x32_bf16(aq[0][kc], kf[nt * 4 + kc], s0, 0, 0, 0);
        s1 = __builtin_amdgcn_mfma_f32_16x16x32_bf16(aq[1][kc], kf[nt * 4 + kc], s1, 0, 0, 0);
      }
      sf[0][nt] = s0;
      sf[1][nt] = s1;
    }

    // batch-issue ALL 16 V-fragment loads (dense 16KB contiguous); kf dead now.
    // sched_barrier(0) pins issues ABOVE the softmax so latency hides under it.
    const ushort* vB = vtg + ((size_t)(b * 64 + i * 16 + wave * 2)) * 4096 + lane * 8;
    s8v vf[16];
#pragma unroll
    for (int f = 0; f < 16; ++f) vf[f] = *(const s8v*)(vB + f * 512);
    __builtin_amdgcn_sched_barrier(0);

    // P = exp(S) (fixed reference 0), accumulate per-lane row sums, store P
#pragma unroll
    for (int m = 0; m < 2; ++m)
#pragma unroll
      for (int g = 0; g < 4; ++g) {
        int rg = q0 + m * 16 + quad * 4 + g;
#pragma unroll
        for (int nt = 0; nt < 4; ++nt) {
          float pv = __expf(sf[m][nt][g]);
          rs[m][g] += pv;  // l over ALL keys (mask is post-softmax, no renorm)
          int jg = kt * 64 + nt * 16 + lc;
          if (domask && (jg <= rg)) pv = 0.f;
          Psw[(m * 16 + quad * 4 + g) * PST + nt * 16 + lc] = pv;
        }
      }

    // P x V: each V fragment feeds both M-tiles' MFMAs
#pragma unroll
    for (int jc = 0; jc < 2; ++jc)
#pragma unroll
      for (int m = 0; m < 2; ++m) {
        const float* pp = &Psw[(m * 16 + lc) * PST + jc * 32 + quad * 8];
        float4 p0 = *(const float4*)pp;
        float4 p1 = *(const float4*)(pp + 4);
        s8v ap;
        ap[0] = (short)f2bf(p0.x); ap[1] = (short)f2bf(p0.y);
        ap[2] = (short)f2bf(p0.z); ap[3] = (short)f2bf(p0.w);
        ap[4] = (short)f2bf(p1.x); ap[5] = (short)f2bf(p1.y);
        ap[6] = (short)f2bf(p1.z); ap[7] = (short)f2bf(p1.w);
#pragma unroll
        for (int dt = 0; dt < 8; ++dt) {
          acc[m][dt] = __builtin_amdgcn_mfma_f32_16x16x32_bf16(ap, vf[jc * 8 + dt], acc[m][dt], 0, 0, 0);
        }
      }
  }

  // reduce per-lane row sums across the 16 lc lanes (once, after the loop)
#pragma unroll
  for (int off = 8; off >= 1; off >>= 1)
#pragma unroll
    for (int m = 0; m < 2; ++m)
#pragma unroll
      for (int g = 0; g < 4; ++g) rs[m][g] += __shfl_xor(rs[m][g], off, 64);

  // all waves done with Ps before the region is reused as accS
  __syncthreads();
  if (lc == 0) {
#pragma unroll
    for (int m = 0; m < 2; ++m)
#pragma unroll
      for (int g = 0; g < 4; ++g) lS[wave][m][quad * 4 + g] = rs[m][g];
  }

  // merge the 8 per-wave partials (plain sums — same softmax reference for all),
  // one 16-row M-tile at a time; FULLY unrolled so acc[] indices stay static.
#pragma unroll
  for (int m = 0; m < 2; ++m) {
#pragma unroll
    for (int dt = 0; dt < 8; ++dt)
#pragma unroll
      for (int g = 0; g < 4; ++g)
        smem[wave * (16 * AST) + (quad * 4 + g) * AST + dt * 16 + lc] = acc[m][dt][g];
    __syncthreads();
    {
      int row = t >> 5, c0 = (t & 31) * 4;
      float L = 0.f;
      float ox = 0.f, oy = 0.f, oz = 0.f, ow = 0.f;
#pragma unroll
      for (int p = 0; p < 8; ++p) {
        L += lS[p][m][row];
        const float* a = &smem[p * (16 * AST) + row * AST + c0];
        float4 xv = *(const float4*)a;
        ox += xv.x; oy += xv.y; oz += xv.z; ow += xv.w;
      }
      float inv = 1.0f / L;
      float4 o;
      o.x = ox * inv; o.y = oy * inv; o.z = oz * inv; o.w = ow * inv;
      float* op = out + ((size_t)(b * LQ + q0 + m * 16 + row)) * PDD + c0;
      *(float4*)op = o;
    }
    __syncthreads();  // merge reads done before next phase overwrites accS
  }
}

extern "C" void kernel_launch(void* const* d_in, const int* in_sizes, int n_in,
                              void* d_out, int out_size, void* d_ws, size_t ws_size,
                              hipStream_t stream) {
  const float* x  = (const float*)d_in[0];
  const float* y  = (const float*)d_in[1];
  const float* Wq = (const float*)d_in[2];
  const float* bq = (const float*)d_in[3];
  const float* Wk = (const float*)d_in[4];
  const float* bk = (const float*)d_in[5];
  const float* Wv = (const float*)d_in[6];
  const float* bv = (const float*)d_in[7];
  const int* mask = (const int*)d_in[8];
  char* ws = (char*)d_ws;
  ushort* qb = (ushort*)(ws);                     // qb2: [B][128][4][4][16][8] bf16
  ushort* kb = (ushort*)(ws + (size_t)(1 << 21)); // kb2: [B][128][4][4][16][8] bf16
  ushort* vt = (ushort*)(ws + (size_t)(2 << 21)); // vb2: [B][64][8][4][16][8] bf16
  ushort* Wt = (ushort*)(ws + (size_t)(3 << 21)); // Wt2: fragment-contiguous [3][...]
  float* out = (float*)d_out;

  hipLaunchKernelGGL(k_wtrans, dim3(32, 3), dim3(256), 0, stream, Wq, Wk, Wv, Wt);
  hipLaunchKernelGGL(k_proj, dim3(512), dim3(256), 0, stream, x, y, Wt, bq, bk, bv, qb, kb, vt);
  hipLaunchKernelGGL(k_attn, dim3(256), dim3(512), 0, stream, qb, kb, vt, mask, out);
}